// Round 3
// baseline (295.090 us; speedup 1.0000x reference)
//
#include <hip/hip_runtime.h>
#include <math.h>

#define Bc 8
#define Nc 1024
#define Dc 1024
#define Hc 16
#define DHc 64
#define NEGINF -1e9f
#define LOG2E 1.44269504f

typedef unsigned int  u32;
typedef unsigned short u16;
typedef unsigned long long u64;
typedef u16  u16x8 __attribute__((ext_vector_type(8)));
typedef u16  u16x4 __attribute__((ext_vector_type(4)));
typedef u32  u32x2 __attribute__((ext_vector_type(2)));
typedef __bf16 bf16x8 __attribute__((ext_vector_type(8)));
typedef float f32x4 __attribute__((ext_vector_type(4)));

__device__ __forceinline__ u16 f2bf(float f) {           // RTNE float->bf16
    u32 u = __builtin_bit_cast(u32, f);
    u += 0x7fffu + ((u >> 16) & 1u);
    return (u16)(u >> 16);
}
__device__ __forceinline__ float bf2f(u16 b) {
    return __builtin_bit_cast(float, (u32)b << 16);
}
// pack two floats' top halves (truncating bf16) into one u32: low16=lo, high16=hi
__device__ __forceinline__ u32 pack2bf(float lo, float hi) {
    return __builtin_amdgcn_perm(__builtin_bit_cast(u32, hi),
                                 __builtin_bit_cast(u32, lo), 0x07060302u);
}
// raw 2^x (v_exp_f32), no ln2 fixup mul, no ocml wrapper
__device__ __forceinline__ float exp2_raw(float x) {
    float r;
    asm("v_exp_f32 %0, %1" : "=v"(r) : "v"(x));
    return r;
}

// async global->LDS, 16 B per lane; LDS dest = wave-uniform base + lane*16.
__device__ __forceinline__ void glds16(const u16* g, const u16* l) {
    __builtin_amdgcn_global_load_lds(
        (const __attribute__((address_space(1))) void*)(u64)g,
        (__attribute__((address_space(3))) void*)(u32)(u64)l, 16, 0, 0);
}

// ---------------------------------------------------------------------------
// Fused prepasses (one kernel, branch on block range):
//  blocks [0, 8192):      sigma-permuted bias (key k -> 4*(k%16)+k/16 within
//                         each 64-block), PRE-MULTIPLIED by log2e so attn can
//                         use fma + raw v_exp_f32 (2^x). NEGINF unscaled is
//                         fine (exp2(-1e9) == 0).
//  blocks [8192, 12288):  hid fp32 -> bf16
//  blocks [12288, 15360): W -> W^T bf16 (z = q/k/v)
// ---------------------------------------------------------------------------
__global__ __launch_bounds__(256) void prep_fused(
    const int* __restrict__ adj, const int* __restrict__ relpos,
    const float* __restrict__ rel_table, u16* __restrict__ bias,
    const float* __restrict__ hid, u16* __restrict__ hidb,
    const float* __restrict__ Wq, const float* __restrict__ Wk,
    const float* __restrict__ Wv, u16* __restrict__ WqT,
    u16* __restrict__ WkT, u16* __restrict__ WvT)
{
    const int blk = blockIdx.x;
    const int t = threadIdx.x;

    if (blk < 8192) {
        __shared__ float tbl[8];
        if (t < 6) tbl[t] = rel_table[t] * LOG2E;
        __syncthreads();
        int i = blk * 256 + t;                 // one u16x4 output
        int pos4 = i << 2;
        int row  = pos4 >> 10;                 // b*N + q
        int p    = pos4 & 1023;
        int blkb = p & ~63;
        int m    = (p & 63) >> 2;              // 0..15
        size_t base = ((size_t)row << 10) + blkb + m;
        u16x4 o;
#pragma unroll
        for (int j = 0; j < 4; ++j) {          // element j <- plain key 16j+m
            int a  = adj[base + 16 * j];
            int rp = relpos[base + 16 * j];
            o[j] = a ? f2bf(tbl[rp]) : f2bf(NEGINF);
        }
        ((u16x4*)bias)[i] = o;
    } else if (blk < 12288) {
        int idx = (blk - 8192) * 256 + t;      // per 8 elements
        float4 a = ((const float4*)hid)[2 * idx];
        float4 b = ((const float4*)hid)[2 * idx + 1];
        u16x8 o;
        o[0] = f2bf(a.x); o[1] = f2bf(a.y); o[2] = f2bf(a.z); o[3] = f2bf(a.w);
        o[4] = f2bf(b.x); o[5] = f2bf(b.y); o[6] = f2bf(b.z); o[7] = f2bf(b.w);
        ((u16x8*)hidb)[idx] = o;
    } else {
        __shared__ float tile[32][33];
        const int wb = blk - 12288;
        const int x = wb & 31, y = (wb >> 5) & 31, z = wb >> 10;
        const float* W; u16* WT;
        if (z == 0)      { W = Wq; WT = WqT; }
        else if (z == 1) { W = Wk; WT = WkT; }
        else             { W = Wv; WT = WvT; }
        const int tx = t & 31, ty = t >> 5;    // (32, 8)
        const int n0 = x * 32, k0 = y * 32;
#pragma unroll
        for (int i = 0; i < 4; ++i) {
            int r = ty + i * 8;
            tile[r][tx] = W[(size_t)(k0 + r) * Dc + n0 + tx];
        }
        __syncthreads();
#pragma unroll
        for (int i = 0; i < 4; ++i) {
            int n = ty + i * 8;
            WT[(size_t)(n0 + n) * Dc + k0 + tx] = f2bf(tile[tx][n]);
        }
    }
}

// ---------------------------------------------------------------------------
// Kernel 1: fused QKV projection (m97-structure), re-merged (r2's split cost
// ~8 us in dispatch-boundary/tail). Grid (64, 24): x = row-panel -> XCD =
// x%8 (linear id%8 = x%8 since 64*y%8==0), so all 24 (z, col-panel) blocks of
// a row-panel share an XCD: hid A-panel fetched once per XCD, L2-hot.
// z = y>>3 selects Q/K/V. Q output PRE-SCALED by 1/32 (exact, power of two).
// q,k out: bf16 [B,H,N,DH], d sigma-permuted per 64-block.
// v out: bf16 [B,H,DH,N], key dim sigma-permuted per 64-block.
// ---------------------------------------------------------------------------
__global__ __launch_bounds__(256) void qkv_mfma(
    const u16* __restrict__ hidb, const u16* __restrict__ WqT,
    const u16* __restrict__ WkT, const u16* __restrict__ WvT,
    u16* __restrict__ qo, u16* __restrict__ ko, u16* __restrict__ vo)
{
    __shared__ u16 As[128 * 64];
    __shared__ u16 Bs[128 * 64];

    const int by = blockIdx.y;
    const int z = by >> 3;
    const int c0 = (by & 7) << 7;             // within-z col base
    const int row0 = blockIdx.x << 7;         // global row base (b*N + n)
    const u16* WT; u16* out;
    if (z == 0)      { WT = WqT; out = qo; }
    else if (z == 1) { WT = WkT; out = ko; }
    else             { WT = WvT; out = vo; }
    const float qsc = (z == 0) ? 0.03125f : 1.0f;   // fold 1/sqrt(D) into Q

    const int tid = threadIdx.x;
    const int wave = tid >> 6, lane = tid & 63;
    const int g = lane >> 4, li = lane & 15;
    const int wr = wave >> 1, wc = wave & 1;
    const int lr = lane >> 3, ls = lane & 7;  // staging: row-in-group, seg
    const int sseg = ls ^ lr;                 // swizzled k-segment to fetch

    const u16* pa = hidb + (size_t)(row0 + wave * 32 + lr) * Dc + sseg * 8;
    const u16* pb = WT   + (size_t)(c0   + wave * 32 + lr) * Dc + sseg * 8;
    u16* la = &As[(wave * 32) * 64];
    u16* lb = &Bs[(wave * 32) * 64];

    f32x4 acc[4][4] = {};

    const int swz = (li & 7);                 // fragment-read swizzle key

    for (int kt = 0; kt < Dc; kt += 64) {
        __syncthreads();
#pragma unroll
        for (int i = 0; i < 4; ++i) {
            glds16(pa + kt + i * 8 * Dc, la + i * 8 * 64);
            glds16(pb + kt + i * 8 * Dc, lb + i * 8 * 64);
        }
        __syncthreads();
#pragma unroll
        for (int ks = 0; ks < 2; ++ks) {
            const int soff = ((ks * 4 + g) ^ swz) * 8;
            bf16x8 af[4], bf[4];
#pragma unroll
            for (int mi = 0; mi < 4; ++mi)
                af[mi] = *(const bf16x8*)&As[(wr * 64 + mi * 16 + li) * 64 + soff];
#pragma unroll
            for (int nj = 0; nj < 4; ++nj)
                bf[nj] = *(const bf16x8*)&Bs[(wc * 64 + nj * 16 + li) * 64 + soff];
#pragma unroll
            for (int mi = 0; mi < 4; ++mi)
#pragma unroll
                for (int nj = 0; nj < 4; ++nj)
                    acc[mi][nj] = __builtin_amdgcn_mfma_f32_16x16x32_bf16(
                        af[mi], bf[nj], acc[mi][nj], 0, 0, 0);
        }
    }

    const int b = row0 >> 10;

    if (z != 2) {
        // sigma-d epilogue: lane's 4 cols {li,li+16,li+32,li+48} -> sigma
        // positions 4*li..4*li+3 (contiguous): one b64 RTNE store per (mi,rr)
        const int h2 = (c0 + wc * 64) >> 6;
        const int nbase = (row0 & 1023) + wr * 64 + g * 4;
#pragma unroll
        for (int mi = 0; mi < 4; ++mi)
#pragma unroll
            for (int rr = 0; rr < 4; ++rr) {
                int n = nbase + mi * 16 + rr;
                u32x2 pk;
                pk.x = (u32)f2bf(acc[mi][0][rr] * qsc) | ((u32)f2bf(acc[mi][1][rr] * qsc) << 16);
                pk.y = (u32)f2bf(acc[mi][2][rr] * qsc) | ((u32)f2bf(acc[mi][3][rr] * qsc) << 16);
                *(u32x2*)(out + ((size_t)(b * Hc + h2) * Nc + n) * DHc + 4 * li) = pk;
            }
    } else {
        // per-wave 64x64 transpose in LDS scratch; key dim stored in
        // sigma-permuted order with the usual XOR seg swizzle.
        __syncthreads();
        u16* T = ((wave & 2) ? Bs : As) + (wave & 1) * 4096;
#pragma unroll
        for (int mi = 0; mi < 4; ++mi)
#pragma unroll
            for (int rr = 0; rr < 4; ++rr) {
                int r = mi * 16 + g * 4 + rr;
                int pp = ((r & 15) << 2) | (r >> 4);     // sigma(r)
#pragma unroll
                for (int nj = 0; nj < 4; ++nj) {
                    int c = nj * 16 + li;
                    T[c * 64 + ((((pp >> 3) ^ (c & 7)) << 3) | (pp & 7))]
                        = f2bf(acc[mi][nj][rr]);
                }
            }
        const int nseg = ls ^ lr;
#pragma unroll
        for (int i = 0; i < 8; ++i) {
            int cl = i * 8 + lr;              // local col (d)
            u16x8 val = *(const u16x8*)&T[cl * 64 + ls * 8];
            int cz = c0 + wc * 64 + cl;
            int n = (row0 & 1023) + wr * 64 + nseg * 8;
            *(u16x8*)&vo[(((size_t)(b * Hc + (cz >> 6)) * DHc + (cz & 63)) * Nc) + n] = val;
        }
    }
}

// ---------------------------------------------------------------------------
// Kernel 2: flash attention v4 — 40 KB LDS -> 4 blocks/CU (1024 blocks =
// 4 x 256 CUs: FULL residency, zero tail). r2 counters showed latency-bound
// (VALU 47%, Mfma 22%, HBM 17%, occ 23.6%): the lever is overlap, not pipes.
//  - K double-buffered (16 KB); V SINGLE-buffered (8 KB): V[it] glds issue
//    after barrier B1, drained by B2 (QK+softmax = latency cover); V[it+1]
//    cannot race (PV readers all passed next B1).
//  - K[it+1] glds issue after B2 (PV phase = cover), drained at next B1.
//  - PQ 16 KB via 16B-grain XOR swizzle (off ^ (row&7)<<3) instead of +8 pad;
//    applied consistently on Q-stage write / qf read / P write / P read.
//  - softmax: bias premul'd by log2e in prep -> P = v_exp_f32(fma(s,log2e,b)).
// Fixed-max softmax (max==0 safe); q pre-scaled by 1/32 in qkv.
// ---------------------------------------------------------------------------
__global__ __launch_bounds__(256, 4) void attn_mfma(
    const u16* __restrict__ q, const u16* __restrict__ k,
    const u16* __restrict__ v, const u16* __restrict__ bias,
    float* __restrict__ attn_out)
{
    __shared__ u16 Ks[2][64 * 64];    // 16 KB [buf][key][kseg^(key&7)]
    __shared__ u16 VTs[64 * 64];      // 8 KB  [d][pkseg^(d&7)], single buffer
    __shared__ u16 PQ[128 * 64];      // 16 KB Q then P, XOR-swizzled rows

    const int tid = threadIdx.x;
    const int w = tid >> 6, lane = tid & 63;
    const int g = lane >> 4, li = lane & 15;
    const int lr8 = lane >> 3, ls8 = lane & 7;
    const int lseg = ls8 ^ lr8;               // swizzled staging k-seg

    // XCD-locality remap: whole batch element b on XCD (id & 7); h fastest.
    const int id = blockIdx.x;
    const int b  = id & 7;
    const int r_ = id >> 3;                   // 0..127
    const int h  = r_ & 15;
    const int qt = r_ >> 4;
    const int q0 = qt << 7;

    const u16* kbase = k + (size_t)(b * Hc + h) * Nc * DHc;
    const u16* vbase = v + (size_t)(b * Hc + h) * DHc * Nc;
    const u16* brow  = bias + ((size_t)(b * Nc) + q0 + w * 32) * Nc + 4 * li;

    // ---- prologue: K tile 0 ----
    {
        const u16* kp = kbase + (size_t)(w * 16 + lr8) * DHc + lseg * 8;
        glds16(kp,           &Ks[0][(w * 16) * 64]);
        glds16(kp + 8 * DHc, &Ks[0][(w * 16) * 64 + 8 * 64]);
    }

    // ---- stage Q [128][64] into PQ, swizzled (wave-private rows) ----
    {
        const int sr = tid >> 1;
        const int sh = (tid & 1) * 32;
        const int sw = (sr & 7) << 3;
        const u16* qp = q + ((size_t)((b * Hc + h) * Nc) + q0 + sr) * DHc + sh;
        u16* dst = &PQ[sr * 64];
        *(u16x8*)(dst + ((sh +  0) ^ sw)) = *(const u16x8*)(qp);
        *(u16x8*)(dst + ((sh +  8) ^ sw)) = *(const u16x8*)(qp + 8);
        *(u16x8*)(dst + ((sh + 16) ^ sw)) = *(const u16x8*)(qp + 16);
        *(u16x8*)(dst + ((sh + 24) ^ sw)) = *(const u16x8*)(qp + 24);
    }

    // bias tile 0 prefetch
    u16x4 brv[2][4];
#pragma unroll
    for (int mt = 0; mt < 2; ++mt)
#pragma unroll
        for (int r = 0; r < 4; ++r)
            brv[mt][r] = *(const u16x4*)&brow[(size_t)(mt * 16 + g * 4 + r) * Nc];

    // Q fragments (intra-wave LDS dependency only)
    bf16x8 qf[2][2];
#pragma unroll
    for (int mt = 0; mt < 2; ++mt)
#pragma unroll
        for (int ks = 0; ks < 2; ++ks)
            qf[mt][ks] = *(const bf16x8*)&PQ[(w * 32 + mt * 16 + li) * 64
                                            + ((ks * 32 + g * 8) ^ ((li & 7) << 3))];

    f32x4 o_[2][4] = {};
    float lsum[2][4] = {};

    for (int it = 0; it < 16; ++it) {
        const int cur = it & 1;
        __syncthreads();   // B1: K[it] drained; VTs free (all PV[it-1] done)

        // V tile it into the single buffer (drained at B2; QK+softmax cover)
        {
            const u16* vp = vbase + (size_t)(w * 16 + lr8) * Nc + it * 64 + lseg * 8;
            glds16(vp,          &VTs[(w * 16) * 64]);
            glds16(vp + 8 * Nc, &VTs[(w * 16) * 64 + 8 * 64]);
        }

        // --- S = Q.K^T : 16 MFMA, 8 K-frag b128 reads ---
        f32x4 sacc[2][4] = {};
        __builtin_amdgcn_s_setprio(1);
#pragma unroll
        for (int ks = 0; ks < 2; ++ks) {
            const int so = (((ks << 2) | g) ^ (li & 7)) << 3;
#pragma unroll
            for (int nt = 0; nt < 4; ++nt) {
                bf16x8 kf = *(const bf16x8*)&Ks[cur][(nt * 16 + li) * 64 + so];
                sacc[0][nt] = __builtin_amdgcn_mfma_f32_16x16x32_bf16(qf[0][ks], kf, sacc[0][nt], 0, 0, 0);
                sacc[1][nt] = __builtin_amdgcn_mfma_f32_16x16x32_bf16(qf[1][ks], kf, sacc[1][nt], 0, 0, 0);
            }
        }
        __builtin_amdgcn_s_setprio(0);

        // --- softmax: P = 2^(fma(s, log2e, bias2)); packed b64 in sigma-space ---
#pragma unroll
        for (int mt = 0; mt < 2; ++mt)
#pragma unroll
            for (int r = 0; r < 4; ++r) {
                const int qrl = w * 32 + mt * 16 + g * 4 + r;
                float pv[4];
#pragma unroll
                for (int nt = 0; nt < 4; ++nt) {
                    pv[nt] = exp2_raw(fmaf(sacc[mt][nt][r], LOG2E,
                                           bf2f(brv[mt][r][nt])));
                    lsum[mt][r] += pv[nt];
                }
                u32* dst = (u32*)&PQ[(qrl & ~7) * 64
                                     + (((qrl & 7) * 64 + li * 4) ^ ((qrl & 7) << 3))];
                dst[0] = pack2bf(pv[0], pv[1]);
                dst[1] = pack2bf(pv[2], pv[3]);
            }

        __syncthreads();   // B2: V[it] drained+visible; waves re-synced

        // --- O += P.V : 16 MFMA, 4 P-frag + 8 VT-frag b128 reads ---
        __builtin_amdgcn_s_setprio(1);
#pragma unroll
        for (int ks = 0; ks < 2; ++ks) {
            const int so = (((ks << 2) | g) ^ (li & 7)) << 3;
            const int po = (ks * 32 + g * 8) ^ ((li & 7) << 3);
            bf16x8 pa0 = *(const bf16x8*)&PQ[(w * 32 + li) * 64 + po];
            bf16x8 pa1 = *(const bf16x8*)&PQ[(w * 32 + 16 + li) * 64 + po];
#pragma unroll
            for (int j = 0; j < 4; ++j) {
                bf16x8 vf = *(const bf16x8*)&VTs[(j * 16 + li) * 64 + so];
                o_[0][j] = __builtin_amdgcn_mfma_f32_16x16x32_bf16(pa0, vf, o_[0][j], 0, 0, 0);
                o_[1][j] = __builtin_amdgcn_mfma_f32_16x16x32_bf16(pa1, vf, o_[1][j], 0, 0, 0);
            }
        }
        __builtin_amdgcn_s_setprio(0);

        // K[it+1] + bias[it+1] prefetch (PV above + next-iter top = cover;
        // Ks[cur^1] readers all finished before B2)
        if (it < 15) {
            const int k1 = (it + 1) * 64;
            const u16* kp = kbase + (size_t)(k1 + w * 16 + lr8) * DHc + lseg * 8;
            glds16(kp,           &Ks[cur ^ 1][(w * 16) * 64]);
            glds16(kp + 8 * DHc, &Ks[cur ^ 1][(w * 16) * 64 + 8 * 64]);
#pragma unroll
            for (int mt = 0; mt < 2; ++mt)
#pragma unroll
                for (int r = 0; r < 4; ++r)
                    brv[mt][r] = *(const u16x4*)&brow[(size_t)(mt * 16 + g * 4 + r) * Nc + k1];
        }
    }

    // --- epilogue: reduce row sums across 16 li lanes, normalize, write ---
#pragma unroll
    for (int mt = 0; mt < 2; ++mt)
#pragma unroll
        for (int r = 0; r < 4; ++r) {
            float l = lsum[mt][r];
            l += __shfl_xor(l, 1);
            l += __shfl_xor(l, 2);
            l += __shfl_xor(l, 4);
            l += __shfl_xor(l, 8);
            float inv = 1.f / l;
            int qrow = q0 + w * 32 + mt * 16 + g * 4 + r;
            float* op = attn_out + ((size_t)b * Nc + qrow) * Dc + h * DHc;
#pragma unroll
            for (int j = 0; j < 4; ++j)
                op[j * 16 + li] = o_[mt][j][r] * inv;
        }
}

// ---------------------------------------------------------------------------
// Kernel 3: out = LayerNorm(relu(attn_out) + hid), in-place safe.
// ---------------------------------------------------------------------------
__global__ __launch_bounds__(256) void ln_kernel(
    const float* attn_out, const float* __restrict__ hid,
    const float* __restrict__ gamma, const float* __restrict__ beta,
    float* out)
{
    const int row = blockIdx.x;
    const int t = threadIdx.x;

    float4 av = *(const float4*)&attn_out[(size_t)row * Dc + t * 4];
    float4 hv = *(const float4*)&hid[(size_t)row * Dc + t * 4];
    float x0 = fmaxf(av.x, 0.f) + hv.x;
    float x1 = fmaxf(av.y, 0.f) + hv.y;
    float x2 = fmaxf(av.z, 0.f) + hv.z;
    float x3 = fmaxf(av.w, 0.f) + hv.w;

    float s1 = x0 + x1 + x2 + x3;
    float s2 = x0 * x0 + x1 * x1 + x2 * x2 + x3 * x3;
#pragma unroll
    for (int off = 1; off < 64; off <<= 1) {
        s1 += __shfl_xor(s1, off);
        s2 += __shfl_xor(s2, off);
    }
    __shared__ float w1[4], w2[4];
    int lane = t & 63, wid = t >> 6;
    if (lane == 0) { w1[wid] = s1; w2[wid] = s2; }
    __syncthreads();
    s1 = w1[0] + w1[1] + w1[2] + w1[3];
    s2 = w2[0] + w2[1] + w2[2] + w2[3];

    float mu  = s1 * (1.f / 1024.f);
    float var = s2 * (1.f / 1024.f) - mu * mu;
    float rstd = rsqrtf(var + 1e-5f);

    float4 g  = *(const float4*)&gamma[t * 4];
    float4 be = *(const float4*)&beta[t * 4];
    float4 r4;
    r4.x = (x0 - mu) * rstd * g.x + be.x;
    r4.y = (x1 - mu) * rstd * g.y + be.y;
    r4.z = (x2 - mu) * rstd * g.z + be.z;
    r4.w = (x3 - mu) * rstd * g.w + be.w;
    *(float4*)&out[(size_t)row * Dc + t * 4] = r4;
}

extern "C" void kernel_launch(void* const* d_in, const int* in_sizes, int n_in,
                              void* d_out, int out_size, void* d_ws, size_t ws_size,
                              hipStream_t stream) {
    const float* hid       = (const float*)d_in[0];
    const int*   adj       = (const int*)d_in[1];
    const int*   relpos    = (const int*)d_in[2];
    const float* Wq        = (const float*)d_in[3];
    const float* Wk        = (const float*)d_in[4];
    const float* Wv        = (const float*)d_in[5];
    const float* rel_table = (const float*)d_in[6];
    const float* gamma     = (const float*)d_in[7];
    const float* beta      = (const float*)d_in[8];
    float* out = (float*)d_out;

    const size_t per  = (size_t)Bc * Hc * Nc * DHc;  // 8,388,608
    const size_t wsz  = (size_t)Dc * Dc;             // 1,048,576
    u16* qb   = (u16*)d_ws;                // sigma-d, pre-scaled by 1/32
    u16* kb   = qb + per;                  // sigma-d
    u16* vb   = kb + per;                  // [B,H,DH,N] transposed+sigma-key
    u16* bias = vb + per;                  // B*N*N sigma-key-permuted, *log2e
    u16* hidb = bias + (size_t)Bc * Nc * Nc;
    u16* wqT  = hidb + (size_t)Bc * Nc * Dc;
    u16* wkT  = wqT + wsz;
    u16* wvT  = wkT + wsz;
    // total ws: ~90.2 MB

    prep_fused<<<15360, 256, 0, stream>>>(adj, relpos, rel_table, bias,
                                          hid, hidb, Wq, Wk, Wv, wqT, wkT, wvT);
    qkv_mfma<<<dim3(64, 24), 256, 0, stream>>>(hidb, wqT, wkT, wvT, qb, kb, vb);
    attn_mfma<<<1024, 256, 0, stream>>>(qb, kb, vb, bias, out);
    ln_kernel<<<Bc * Nc, 256, 0, stream>>>(out, hid, gamma, beta, out);
}

// Round 5
// 283.053 us; speedup vs baseline: 1.0425x; 1.0425x over previous
//
#include <hip/hip_runtime.h>
#include <math.h>

#define Bc 8
#define Nc 1024
#define Dc 1024
#define Hc 16
#define DHc 64
#define NEGINF -1e9f
#define LOG2E 1.44269504f

typedef unsigned int  u32;
typedef unsigned short u16;
typedef unsigned long long u64;
typedef u16  u16x8 __attribute__((ext_vector_type(8)));
typedef u16  u16x4 __attribute__((ext_vector_type(4)));
typedef u32  u32x2 __attribute__((ext_vector_type(2)));
typedef __bf16 bf16x8 __attribute__((ext_vector_type(8)));
typedef float f32x4 __attribute__((ext_vector_type(4)));

__device__ __forceinline__ u16 f2bf(float f) {           // RTNE float->bf16
    u32 u = __builtin_bit_cast(u32, f);
    u += 0x7fffu + ((u >> 16) & 1u);
    return (u16)(u >> 16);
}
__device__ __forceinline__ float bf2f(u16 b) {
    return __builtin_bit_cast(float, (u32)b << 16);
}
// pack two floats' top halves (truncating bf16) into one u32: low16=lo, high16=hi
__device__ __forceinline__ u32 pack2bf(float lo, float hi) {
    return __builtin_amdgcn_perm(__builtin_bit_cast(u32, hi),
                                 __builtin_bit_cast(u32, lo), 0x07060302u);
}
// raw 2^x (v_exp_f32)
__device__ __forceinline__ float exp2_raw(float x) {
    float r;
    asm("v_exp_f32 %0, %1" : "=v"(r) : "v"(x));
    return r;
}

// async global->LDS, 16 B per lane; LDS dest = wave-uniform base + lane*16.
__device__ __forceinline__ void glds16(const u16* g, const u16* l) {
    __builtin_amdgcn_global_load_lds(
        (const __attribute__((address_space(1))) void*)(u64)g,
        (__attribute__((address_space(3))) void*)(u32)(u64)l, 16, 0, 0);
}

// ---------------------------------------------------------------------------
// Fused prepasses (one kernel, branch on block range):
//  blocks [0, 8192):      sigma-permuted bias (key k -> 4*(k%16)+k/16 within
//                         each 64-block), PRE-MULTIPLIED by log2e so attn can
//                         use fma + raw v_exp_f32 (2^x). NEGINF unscaled is
//                         fine (exp2(-1e9) == 0).
//  blocks [8192, 12288):  hid fp32 -> bf16
//  blocks [12288, 15360): W -> W^T bf16 (z = q/k/v)
// ---------------------------------------------------------------------------
__global__ __launch_bounds__(256) void prep_fused(
    const int* __restrict__ adj, const int* __restrict__ relpos,
    const float* __restrict__ rel_table, u16* __restrict__ bias,
    const float* __restrict__ hid, u16* __restrict__ hidb,
    const float* __restrict__ Wq, const float* __restrict__ Wk,
    const float* __restrict__ Wv, u16* __restrict__ WqT,
    u16* __restrict__ WkT, u16* __restrict__ WvT)
{
    const int blk = blockIdx.x;
    const int t = threadIdx.x;

    if (blk < 8192) {
        __shared__ float tbl[8];
        if (t < 6) tbl[t] = rel_table[t] * LOG2E;
        __syncthreads();
        int i = blk * 256 + t;                 // one u16x4 output
        int pos4 = i << 2;
        int row  = pos4 >> 10;                 // b*N + q
        int p    = pos4 & 1023;
        int blkb = p & ~63;
        int m    = (p & 63) >> 2;              // 0..15
        size_t base = ((size_t)row << 10) + blkb + m;
        u16x4 o;
#pragma unroll
        for (int j = 0; j < 4; ++j) {          // element j <- plain key 16j+m
            int a  = adj[base + 16 * j];
            int rp = relpos[base + 16 * j];
            o[j] = a ? f2bf(tbl[rp]) : f2bf(NEGINF);
        }
        ((u16x4*)bias)[i] = o;
    } else if (blk < 12288) {
        int idx = (blk - 8192) * 256 + t;      // per 8 elements
        float4 a = ((const float4*)hid)[2 * idx];
        float4 b = ((const float4*)hid)[2 * idx + 1];
        u16x8 o;
        o[0] = f2bf(a.x); o[1] = f2bf(a.y); o[2] = f2bf(a.z); o[3] = f2bf(a.w);
        o[4] = f2bf(b.x); o[5] = f2bf(b.y); o[6] = f2bf(b.z); o[7] = f2bf(b.w);
        ((u16x8*)hidb)[idx] = o;
    } else {
        __shared__ float tile[32][33];
        const int wb = blk - 12288;
        const int x = wb & 31, y = (wb >> 5) & 31, z = wb >> 10;
        const float* W; u16* WT;
        if (z == 0)      { W = Wq; WT = WqT; }
        else if (z == 1) { W = Wk; WT = WkT; }
        else             { W = Wv; WT = WvT; }
        const int tx = t & 31, ty = t >> 5;    // (32, 8)
        const int n0 = x * 32, k0 = y * 32;
#pragma unroll
        for (int i = 0; i < 4; ++i) {
            int r = ty + i * 8;
            tile[r][tx] = W[(size_t)(k0 + r) * Dc + n0 + tx];
        }
        __syncthreads();
#pragma unroll
        for (int i = 0; i < 4; ++i) {
            int n = ty + i * 8;
            WT[(size_t)(n0 + n) * Dc + k0 + tx] = f2bf(tile[tx][n]);
        }
    }
}

// ---------------------------------------------------------------------------
// Kernel 1: fused QKV projection (m97-structure). Grid (64, 24): x = row-panel
// -> XCD = x%8, so all 24 (z, col-panel) blocks of a row-panel share an XCD:
// hid A-panel fetched once per XCD, L2-hot.
// z = y>>3 selects Q/K/V. Q output PRE-SCALED by 1/32 (exact, power of two).
// q,k out: bf16 [B,H,N,DH], d sigma-permuted per 64-block.
// v out: bf16 [B,H,DH,N], key dim sigma-permuted per 64-block.
// ---------------------------------------------------------------------------
__global__ __launch_bounds__(256) void qkv_mfma(
    const u16* __restrict__ hidb, const u16* __restrict__ WqT,
    const u16* __restrict__ WkT, const u16* __restrict__ WvT,
    u16* __restrict__ qo, u16* __restrict__ ko, u16* __restrict__ vo)
{
    __shared__ u16 As[128 * 64];
    __shared__ u16 Bs[128 * 64];

    const int by = blockIdx.y;
    const int z = by >> 3;
    const int c0 = (by & 7) << 7;             // within-z col base
    const int row0 = blockIdx.x << 7;         // global row base (b*N + n)
    const u16* WT; u16* out;
    if (z == 0)      { WT = WqT; out = qo; }
    else if (z == 1) { WT = WkT; out = ko; }
    else             { WT = WvT; out = vo; }
    const float qsc = (z == 0) ? 0.03125f : 1.0f;   // fold 1/sqrt(D) into Q

    const int tid = threadIdx.x;
    const int wave = tid >> 6, lane = tid & 63;
    const int g = lane >> 4, li = lane & 15;
    const int wr = wave >> 1, wc = wave & 1;
    const int lr = lane >> 3, ls = lane & 7;  // staging: row-in-group, seg
    const int sseg = ls ^ lr;                 // swizzled k-segment to fetch

    const u16* pa = hidb + (size_t)(row0 + wave * 32 + lr) * Dc + sseg * 8;
    const u16* pb = WT   + (size_t)(c0   + wave * 32 + lr) * Dc + sseg * 8;
    u16* la = &As[(wave * 32) * 64];
    u16* lb = &Bs[(wave * 32) * 64];

    f32x4 acc[4][4] = {};

    const int swz = (li & 7);                 // fragment-read swizzle key

    for (int kt = 0; kt < Dc; kt += 64) {
        __syncthreads();
#pragma unroll
        for (int i = 0; i < 4; ++i) {
            glds16(pa + kt + i * 8 * Dc, la + i * 8 * 64);
            glds16(pb + kt + i * 8 * Dc, lb + i * 8 * 64);
        }
        __syncthreads();
#pragma unroll
        for (int ks = 0; ks < 2; ++ks) {
            const int soff = ((ks * 4 + g) ^ swz) * 8;
            bf16x8 af[4], bf[4];
#pragma unroll
            for (int mi = 0; mi < 4; ++mi)
                af[mi] = *(const bf16x8*)&As[(wr * 64 + mi * 16 + li) * 64 + soff];
#pragma unroll
            for (int nj = 0; nj < 4; ++nj)
                bf[nj] = *(const bf16x8*)&Bs[(wc * 64 + nj * 16 + li) * 64 + soff];
#pragma unroll
            for (int mi = 0; mi < 4; ++mi)
#pragma unroll
                for (int nj = 0; nj < 4; ++nj)
                    acc[mi][nj] = __builtin_amdgcn_mfma_f32_16x16x32_bf16(
                        af[mi], bf[nj], acc[mi][nj], 0, 0, 0);
        }
    }

    const int b = row0 >> 10;

    if (z != 2) {
        // sigma-d epilogue: lane's 4 cols {li,li+16,li+32,li+48} -> sigma
        // positions 4*li..4*li+3 (contiguous): one b64 RTNE store per (mi,rr)
        const int h2 = (c0 + wc * 64) >> 6;
        const int nbase = (row0 & 1023) + wr * 64 + g * 4;
#pragma unroll
        for (int mi = 0; mi < 4; ++mi)
#pragma unroll
            for (int rr = 0; rr < 4; ++rr) {
                int n = nbase + mi * 16 + rr;
                u32x2 pk;
                pk.x = (u32)f2bf(acc[mi][0][rr] * qsc) | ((u32)f2bf(acc[mi][1][rr] * qsc) << 16);
                pk.y = (u32)f2bf(acc[mi][2][rr] * qsc) | ((u32)f2bf(acc[mi][3][rr] * qsc) << 16);
                *(u32x2*)(out + ((size_t)(b * Hc + h2) * Nc + n) * DHc + 4 * li) = pk;
            }
    } else {
        // per-wave 64x64 transpose in LDS scratch; key dim stored in
        // sigma-permuted order with the usual XOR seg swizzle.
        __syncthreads();
        u16* T = ((wave & 2) ? Bs : As) + (wave & 1) * 4096;
#pragma unroll
        for (int mi = 0; mi < 4; ++mi)
#pragma unroll
            for (int rr = 0; rr < 4; ++rr) {
                int r = mi * 16 + g * 4 + rr;
                int pp = ((r & 15) << 2) | (r >> 4);     // sigma(r)
#pragma unroll
                for (int nj = 0; nj < 4; ++nj) {
                    int c = nj * 16 + li;
                    T[c * 64 + ((((pp >> 3) ^ (c & 7)) << 3) | (pp & 7))]
                        = f2bf(acc[mi][nj][rr]);
                }
            }
        const int nseg = ls ^ lr;
#pragma unroll
        for (int i = 0; i < 8; ++i) {
            int cl = i * 8 + lr;              // local col (d)
            u16x8 val = *(const u16x8*)&T[cl * 64 + ls * 8];
            int cz = c0 + wc * 64 + cl;
            int n = (row0 & 1023) + wr * 64 + nseg * 8;
            *(u16x8*)&vo[(((size_t)(b * Hc + (cz >> 6)) * DHc + (cz & 63)) * Nc) + n] = val;
        }
    }
}

// ---------------------------------------------------------------------------
// Kernel 2: flash attention v5 — single-barrier schedule (r3 post-mortem:
// the two-barrier/V-single-buffer variant raised occupancy 24->35% yet cost
// +12 us: V's glds drain at B2 had only a softmax phase of cover, and 16
// extra block-wide barriers serialize. Lesson: keep prefetch -> drain
// distance = one FULL compute phase).
//  - K AND V double-buffered (32 KB); ALL tile-(it+1) glds + bias prefetch
//    issue right after the single barrier; drain at the next barrier.
//  - PQ 16 KB via 16B-grain XOR swizzle (validated r3: 0 bank conflicts).
//    LDS total 48 KB -> 3 blocks/CU.
//  - softmax: bias premul'd by log2e in prep -> P = v_exp_f32(fma(s,log2e,b))
//    (validated r3: VALUBusy 47->33%, absmax unchanged).
// Fixed-max softmax (max==0 safe); q pre-scaled by 1/32 in qkv.
// XCD swizzle: whole batch element b on XCD (id & 7); h fastest (bias reuse).
// ---------------------------------------------------------------------------
__global__ __launch_bounds__(256, 3) void attn_mfma(
    const u16* __restrict__ q, const u16* __restrict__ k,
    const u16* __restrict__ v, const u16* __restrict__ bias,
    float* __restrict__ attn_out)
{
    __shared__ u16 Ks[2][64 * 64];    // 16 KB [buf][key][kseg^(key&7)]
    __shared__ u16 VTs[2][64 * 64];   // 16 KB [buf][d][pkseg^(d&7)]
    __shared__ u16 PQ[128 * 64];      // 16 KB Q then P, XOR-swizzled rows

    const int tid = threadIdx.x;
    const int w = tid >> 6, lane = tid & 63;
    const int g = lane >> 4, li = lane & 15;
    const int lr8 = lane >> 3, ls8 = lane & 7;
    const int lseg = ls8 ^ lr8;               // swizzled staging k-seg

    // XCD-locality remap: whole batch element b on XCD (id & 7); h fastest.
    const int id = blockIdx.x;
    const int b  = id & 7;
    const int r_ = id >> 3;                   // 0..127
    const int h  = r_ & 15;
    const int qt = r_ >> 4;
    const int q0 = qt << 7;

    const u16* kbase = k + (size_t)(b * Hc + h) * Nc * DHc;
    const u16* vbase = v + (size_t)(b * Hc + h) * DHc * Nc;
    const u16* brow  = bias + ((size_t)(b * Nc) + q0 + w * 32) * Nc + 4 * li;

    // ---- prologue: issue tile-0 K+V staging first (overlap with Q setup) ----
    {
        const u16* kp = kbase + (size_t)(w * 16 + lr8) * DHc + lseg * 8;
        const u16* vp = vbase + (size_t)(w * 16 + lr8) * Nc + lseg * 8;
        glds16(kp,           &Ks[0][(w * 16) * 64]);
        glds16(kp + 8 * DHc, &Ks[0][(w * 16) * 64 + 8 * 64]);
        glds16(vp,           &VTs[0][(w * 16) * 64]);
        glds16(vp + 8 * Nc,  &VTs[0][(w * 16) * 64 + 8 * 64]);
    }

    // ---- stage Q [128][64] into PQ, swizzled (wave-private rows) ----
    {
        const int sr = tid >> 1;
        const int sh = (tid & 1) * 32;
        const int sw = (sr & 7) << 3;
        const u16* qp = q + ((size_t)((b * Hc + h) * Nc) + q0 + sr) * DHc + sh;
        u16* dst = &PQ[sr * 64];
        *(u16x8*)(dst + ((sh +  0) ^ sw)) = *(const u16x8*)(qp);
        *(u16x8*)(dst + ((sh +  8) ^ sw)) = *(const u16x8*)(qp + 8);
        *(u16x8*)(dst + ((sh + 16) ^ sw)) = *(const u16x8*)(qp + 16);
        *(u16x8*)(dst + ((sh + 24) ^ sw)) = *(const u16x8*)(qp + 24);
    }

    // bias tile 0 prefetch
    u16x4 brv[2][4];
#pragma unroll
    for (int mt = 0; mt < 2; ++mt)
#pragma unroll
        for (int r = 0; r < 4; ++r)
            brv[mt][r] = *(const u16x4*)&brow[(size_t)(mt * 16 + g * 4 + r) * Nc];

    // Q fragments (intra-wave LDS dependency only)
    bf16x8 qf[2][2];
#pragma unroll
    for (int mt = 0; mt < 2; ++mt)
#pragma unroll
        for (int ks = 0; ks < 2; ++ks)
            qf[mt][ks] = *(const bf16x8*)&PQ[(w * 32 + mt * 16 + li) * 64
                                            + ((ks * 32 + g * 8) ^ ((li & 7) << 3))];

    f32x4 o_[2][4] = {};
    float lsum[2][4] = {};

    for (int it = 0; it < 16; ++it) {
        const int cur = it & 1;
        __syncthreads();   // drains K[it]+V[it] glds (full-phase-old); syncs bufs

        u16x4 brn[2][4];
        if (it < 15) {     // issue tile it+1 staging into the other buffer
            const int k1 = (it + 1) * 64;
            const u16* kp = kbase + (size_t)(k1 + w * 16 + lr8) * DHc + lseg * 8;
            const u16* vp = vbase + (size_t)(w * 16 + lr8) * Nc + k1 + lseg * 8;
            u16* kl = &Ks[cur ^ 1][(w * 16) * 64];
            u16* vl = &VTs[cur ^ 1][(w * 16) * 64];
            glds16(kp,           kl);
            glds16(kp + 8 * DHc, kl + 8 * 64);
            glds16(vp,           vl);
            glds16(vp + 8 * Nc,  vl + 8 * 64);
#pragma unroll
            for (int mt = 0; mt < 2; ++mt)
#pragma unroll
                for (int r = 0; r < 4; ++r)
                    brn[mt][r] = *(const u16x4*)&brow[(size_t)(mt * 16 + g * 4 + r) * Nc + k1];
        }

        // --- S = Q.K^T : 16 MFMA, 8 K-frag b128 reads ---
        f32x4 sacc[2][4] = {};
        __builtin_amdgcn_s_setprio(1);
#pragma unroll
        for (int ks = 0; ks < 2; ++ks) {
            const int so = (((ks << 2) | g) ^ (li & 7)) << 3;
#pragma unroll
            for (int nt = 0; nt < 4; ++nt) {
                bf16x8 kf = *(const bf16x8*)&Ks[cur][(nt * 16 + li) * 64 + so];
                sacc[0][nt] = __builtin_amdgcn_mfma_f32_16x16x32_bf16(qf[0][ks], kf, sacc[0][nt], 0, 0, 0);
                sacc[1][nt] = __builtin_amdgcn_mfma_f32_16x16x32_bf16(qf[1][ks], kf, sacc[1][nt], 0, 0, 0);
            }
        }
        __builtin_amdgcn_s_setprio(0);

        // --- softmax: P = 2^(fma(s, log2e, bias2)); packed b64 in sigma-space
        //     (PQ rows are wave-private: no barrier between P write and read)
#pragma unroll
        for (int mt = 0; mt < 2; ++mt)
#pragma unroll
            for (int r = 0; r < 4; ++r) {
                const int qrl = w * 32 + mt * 16 + g * 4 + r;
                float pv[4];
#pragma unroll
                for (int nt = 0; nt < 4; ++nt) {
                    pv[nt] = exp2_raw(fmaf(sacc[mt][nt][r], LOG2E,
                                           bf2f(brv[mt][r][nt])));
                    lsum[mt][r] += pv[nt];
                }
                u32* dst = (u32*)&PQ[(qrl & ~7) * 64
                                     + (((qrl & 7) * 64 + li * 4) ^ ((qrl & 7) << 3))];
                dst[0] = pack2bf(pv[0], pv[1]);
                dst[1] = pack2bf(pv[2], pv[3]);
            }

        // --- O += P.V : 16 MFMA, 4 P-frag + 8 VT-frag b128 reads ---
        __builtin_amdgcn_s_setprio(1);
#pragma unroll
        for (int ks = 0; ks < 2; ++ks) {
            const int so = (((ks << 2) | g) ^ (li & 7)) << 3;
            const int po = (ks * 32 + g * 8) ^ ((li & 7) << 3);
            bf16x8 pa0 = *(const bf16x8*)&PQ[(w * 32 + li) * 64 + po];
            bf16x8 pa1 = *(const bf16x8*)&PQ[(w * 32 + 16 + li) * 64 + po];
#pragma unroll
            for (int j = 0; j < 4; ++j) {
                bf16x8 vf = *(const bf16x8*)&VTs[cur][(j * 16 + li) * 64 + so];
                o_[0][j] = __builtin_amdgcn_mfma_f32_16x16x32_bf16(pa0, vf, o_[0][j], 0, 0, 0);
                o_[1][j] = __builtin_amdgcn_mfma_f32_16x16x32_bf16(pa1, vf, o_[1][j], 0, 0, 0);
            }
        }
        __builtin_amdgcn_s_setprio(0);

        if (it < 15) {
#pragma unroll
            for (int mt = 0; mt < 2; ++mt)
#pragma unroll
                for (int r = 0; r < 4; ++r)
                    brv[mt][r] = brn[mt][r];
        }
    }

    // --- epilogue: reduce row sums across 16 li lanes, normalize, write ---
#pragma unroll
    for (int mt = 0; mt < 2; ++mt)
#pragma unroll
        for (int r = 0; r < 4; ++r) {
            float l = lsum[mt][r];
            l += __shfl_xor(l, 1);
            l += __shfl_xor(l, 2);
            l += __shfl_xor(l, 4);
            l += __shfl_xor(l, 8);
            float inv = 1.f / l;
            int qrow = q0 + w * 32 + mt * 16 + g * 4 + r;
            float* op = attn_out + ((size_t)b * Nc + qrow) * Dc + h * DHc;
#pragma unroll
            for (int j = 0; j < 4; ++j)
                op[j * 16 + li] = o_[mt][j][r] * inv;
        }
}

// ---------------------------------------------------------------------------
// Kernel 3: out = LayerNorm(relu(attn_out) + hid), in-place safe.
// ---------------------------------------------------------------------------
__global__ __launch_bounds__(256) void ln_kernel(
    const float* attn_out, const float* __restrict__ hid,
    const float* __restrict__ gamma, const float* __restrict__ beta,
    float* out)
{
    const int row = blockIdx.x;
    const int t = threadIdx.x;

    float4 av = *(const float4*)&attn_out[(size_t)row * Dc + t * 4];
    float4 hv = *(const float4*)&hid[(size_t)row * Dc + t * 4];
    float x0 = fmaxf(av.x, 0.f) + hv.x;
    float x1 = fmaxf(av.y, 0.f) + hv.y;
    float x2 = fmaxf(av.z, 0.f) + hv.z;
    float x3 = fmaxf(av.w, 0.f) + hv.w;

    float s1 = x0 + x1 + x2 + x3;
    float s2 = x0 * x0 + x1 * x1 + x2 * x2 + x3 * x3;
#pragma unroll
    for (int off = 1; off < 64; off <<= 1) {
        s1 += __shfl_xor(s1, off);
        s2 += __shfl_xor(s2, off);
    }
    __shared__ float w1[4], w2[4];
    int lane = t & 63, wid = t >> 6;
    if (lane == 0) { w1[wid] = s1; w2[wid] = s2; }
    __syncthreads();
    s1 = w1[0] + w1[1] + w1[2] + w1[3];
    s2 = w2[0] + w2[1] + w2[2] + w2[3];

    float mu  = s1 * (1.f / 1024.f);
    float var = s2 * (1.f / 1024.f) - mu * mu;
    float rstd = rsqrtf(var + 1e-5f);

    float4 g  = *(const float4*)&gamma[t * 4];
    float4 be = *(const float4*)&beta[t * 4];
    float4 r4;
    r4.x = (x0 - mu) * rstd * g.x + be.x;
    r4.y = (x1 - mu) * rstd * g.y + be.y;
    r4.z = (x2 - mu) * rstd * g.z + be.z;
    r4.w = (x3 - mu) * rstd * g.w + be.w;
    *(float4*)&out[(size_t)row * Dc + t * 4] = r4;
}

extern "C" void kernel_launch(void* const* d_in, const int* in_sizes, int n_in,
                              void* d_out, int out_size, void* d_ws, size_t ws_size,
                              hipStream_t stream) {
    const float* hid       = (const float*)d_in[0];
    const int*   adj       = (const int*)d_in[1];
    const int*   relpos    = (const int*)d_in[2];
    const float* Wq        = (const float*)d_in[3];
    const float* Wk        = (const float*)d_in[4];
    const float* Wv        = (const float*)d_in[5];
    const float* rel_table = (const float*)d_in[6];
    const float* gamma     = (const float*)d_in[7];
    const float* beta      = (const float*)d_in[8];
    float* out = (float*)d_out;

    const size_t per  = (size_t)Bc * Hc * Nc * DHc;  // 8,388,608
    const size_t wsz  = (size_t)Dc * Dc;             // 1,048,576
    u16* qb   = (u16*)d_ws;                // sigma-d, pre-scaled by 1/32
    u16* kb   = qb + per;                  // sigma-d
    u16* vb   = kb + per;                  // [B,H,DH,N] transposed+sigma-key
    u16* bias = vb + per;                  // B*N*N sigma-key-permuted, *log2e
    u16* hidb = bias + (size_t)Bc * Nc * Nc;
    u16* wqT  = hidb + (size_t)Bc * Nc * Dc;
    u16* wkT  = wqT + wsz;
    u16* wvT  = wkT + wsz;
    // total ws: ~90.2 MB

    prep_fused<<<15360, 256, 0, stream>>>(adj, relpos, rel_table, bias,
                                          hid, hidb, Wq, Wk, Wv, wqT, wkT, wvT);
    qkv_mfma<<<dim3(64, 24), 256, 0, stream>>>(hidb, wqT, wkT, wvT, qb, kb, vb);
    attn_mfma<<<1024, 256, 0, stream>>>(qb, kb, vb, bias, out);
    ln_kernel<<<Bc * Nc, 256, 0, stream>>>(out, hid, gamma, beta, out);
}

// Round 7
// 276.233 us; speedup vs baseline: 1.0683x; 1.0247x over previous
//
#include <hip/hip_runtime.h>
#include <math.h>

#define Bc 8
#define Nc 1024
#define Dc 1024
#define Hc 16
#define DHc 64
#define NEGINF -1e9f
#define LOG2E 1.44269504f

typedef unsigned int  u32;
typedef unsigned short u16;
typedef unsigned long long u64;
typedef u16  u16x8 __attribute__((ext_vector_type(8)));
typedef u16  u16x4 __attribute__((ext_vector_type(4)));
typedef u32  u32x2 __attribute__((ext_vector_type(2)));
typedef int  i32x4 __attribute__((ext_vector_type(4)));
typedef __bf16 bf16x8 __attribute__((ext_vector_type(8)));
typedef float f32x4 __attribute__((ext_vector_type(4)));

__device__ __forceinline__ u16 f2bf(float f) {           // RTNE float->bf16
    u32 u = __builtin_bit_cast(u32, f);
    u += 0x7fffu + ((u >> 16) & 1u);
    return (u16)(u >> 16);
}
__device__ __forceinline__ float bf2f(u16 b) {
    return __builtin_bit_cast(float, (u32)b << 16);
}
// pack two floats' top halves (truncating bf16) into one u32: low16=lo, high16=hi
__device__ __forceinline__ u32 pack2bf(float lo, float hi) {
    return __builtin_amdgcn_perm(__builtin_bit_cast(u32, hi),
                                 __builtin_bit_cast(u32, lo), 0x07060302u);
}
// raw 2^x (v_exp_f32)
__device__ __forceinline__ float exp2_raw(float x) {
    float r;
    asm("v_exp_f32 %0, %1" : "=v"(r) : "v"(x));
    return r;
}

// async global->LDS, 16 B per lane; LDS dest = wave-uniform base + lane*16.
__device__ __forceinline__ void glds16(const u16* g, const u16* l) {
    __builtin_amdgcn_global_load_lds(
        (const __attribute__((address_space(1))) void*)(u64)g,
        (__attribute__((address_space(3))) void*)(u32)(u64)l, 16, 0, 0);
}

// ---------------------------------------------------------------------------
// Fused prepasses (one kernel, branch on block range):
//  blocks [0, 2048):     sigma-permuted bias: each thread makes 16 outputs
//                        from 8x int4 (16B) loads (was 8 scalar 4B loads per
//                        4 outputs -> 4x fewer VMEM instructions).
//                        Output pos q (per 64-block) <- key 16(q%4)+q/4;
//                        thread covers q = 16*tt + s (s in 0..15), needing
//                        keys {16u + 4tt + e : u,e in 0..3} = 4 int4
//                        loads/array. Combined select via 8-entry bf16 table:
//                        idx = adj ? rp : 6, tbl[6] = bf16(NEGINF). Bias
//                        pre-multiplied by log2e (exp2 softmax in attn).
//  blocks [2048, 6144):  hid fp32 -> bf16
//  blocks [6144, 9216):  W -> W^T bf16 (z = q/k/v)
// ---------------------------------------------------------------------------
__global__ __launch_bounds__(256) void prep_fused(
    const int* __restrict__ adj, const int* __restrict__ relpos,
    const float* __restrict__ rel_table, u16* __restrict__ bias,
    const float* __restrict__ hid, u16* __restrict__ hidb,
    const float* __restrict__ Wq, const float* __restrict__ Wk,
    const float* __restrict__ Wv, u16* __restrict__ WqT,
    u16* __restrict__ WkT, u16* __restrict__ WvT)
{
    const int blk = blockIdx.x;
    const int t = threadIdx.x;

    if (blk < 2048) {
        __shared__ u16 tblb[8];
        if (t < 8) {
            float v = (t < 6) ? rel_table[t] * LOG2E : NEGINF;
            tblb[t] = f2bf(v);
        }
        __syncthreads();
        const int gid = blk * 256 + t;
        const int o16 = gid << 4;              // base output u16 index
        const int row = o16 >> 10;             // b*N + q
        const int p0  = o16 & 1023;
        const int blkb = p0 & ~63;
        const int tt  = (p0 >> 4) & 3;
        const size_t base = ((size_t)row << 10) + blkb + 4 * tt;
        i32x4 a4[4], r4[4];
#pragma unroll
        for (int u = 0; u < 4; ++u) {
            a4[u] = *(const i32x4*)&adj[base + 16 * u];
            r4[u] = *(const i32x4*)&relpos[base + 16 * u];
        }
        u16x8 o0, o1;
#pragma unroll
        for (int s = 0; s < 8; ++s) {
            const int u = s & 3, e = s >> 2;
            o0[s] = tblb[a4[u][e] ? r4[u][e] : 6];
        }
#pragma unroll
        for (int s = 8; s < 16; ++s) {
            const int u = s & 3, e = s >> 2;
            o1[s - 8] = tblb[a4[u][e] ? r4[u][e] : 6];
        }
        *(u16x8*)&bias[(size_t)o16]     = o0;
        *(u16x8*)&bias[(size_t)o16 + 8] = o1;
    } else if (blk < 6144) {
        int idx = (blk - 2048) * 256 + t;      // per 8 elements
        float4 a = ((const float4*)hid)[2 * idx];
        float4 b = ((const float4*)hid)[2 * idx + 1];
        u16x8 o;
        o[0] = f2bf(a.x); o[1] = f2bf(a.y); o[2] = f2bf(a.z); o[3] = f2bf(a.w);
        o[4] = f2bf(b.x); o[5] = f2bf(b.y); o[6] = f2bf(b.z); o[7] = f2bf(b.w);
        ((u16x8*)hidb)[idx] = o;
    } else {
        __shared__ float tile[32][33];
        const int wb = blk - 6144;
        const int x = wb & 31, y = (wb >> 5) & 31, z = wb >> 10;
        const float* W; u16* WT;
        if (z == 0)      { W = Wq; WT = WqT; }
        else if (z == 1) { W = Wk; WT = WkT; }
        else             { W = Wv; WT = WvT; }
        const int tx = t & 31, ty = t >> 5;    // (32, 8)
        const int n0 = x * 32, k0 = y * 32;
#pragma unroll
        for (int i = 0; i < 4; ++i) {
            int r = ty + i * 8;
            tile[r][tx] = W[(size_t)(k0 + r) * Dc + n0 + tx];
        }
        __syncthreads();
#pragma unroll
        for (int i = 0; i < 4; ++i) {
            int n = ty + i * 8;
            WT[(size_t)(n0 + n) * Dc + k0 + tx] = f2bf(tile[tx][n]);
        }
    }
}

// ---------------------------------------------------------------------------
// Kernel 1: fused QKV projection (m97-structure). Grid (64, 24): x = row-panel
// -> XCD = x%8, so all 24 (z, col-panel) blocks of a row-panel share an XCD:
// hid A-panel fetched once per XCD, L2-hot.
// z = y>>3 selects Q/K/V. Q output PRE-SCALED by 1/32 (exact, power of two).
// q,k out: bf16 [B,H,N,DH], d sigma-permuted per 64-block.
// v out: bf16 [B,H,DH,N], key dim sigma-permuted per 64-block.
// ---------------------------------------------------------------------------
__global__ __launch_bounds__(256) void qkv_mfma(
    const u16* __restrict__ hidb, const u16* __restrict__ WqT,
    const u16* __restrict__ WkT, const u16* __restrict__ WvT,
    u16* __restrict__ qo, u16* __restrict__ ko, u16* __restrict__ vo)
{
    __shared__ u16 As[128 * 64];
    __shared__ u16 Bs[128 * 64];

    const int by = blockIdx.y;
    const int z = by >> 3;
    const int c0 = (by & 7) << 7;             // within-z col base
    const int row0 = blockIdx.x << 7;         // global row base (b*N + n)
    const u16* WT; u16* out;
    if (z == 0)      { WT = WqT; out = qo; }
    else if (z == 1) { WT = WkT; out = ko; }
    else             { WT = WvT; out = vo; }
    const float qsc = (z == 0) ? 0.03125f : 1.0f;   // fold 1/sqrt(D) into Q

    const int tid = threadIdx.x;
    const int wave = tid >> 6, lane = tid & 63;
    const int g = lane >> 4, li = lane & 15;
    const int wr = wave >> 1, wc = wave & 1;
    const int lr = lane >> 3, ls = lane & 7;  // staging: row-in-group, seg
    const int sseg = ls ^ lr;                 // swizzled k-segment to fetch

    const u16* pa = hidb + (size_t)(row0 + wave * 32 + lr) * Dc + sseg * 8;
    const u16* pb = WT   + (size_t)(c0   + wave * 32 + lr) * Dc + sseg * 8;
    u16* la = &As[(wave * 32) * 64];
    u16* lb = &Bs[(wave * 32) * 64];

    f32x4 acc[4][4] = {};

    const int swz = (li & 7);                 // fragment-read swizzle key

    for (int kt = 0; kt < Dc; kt += 64) {
        __syncthreads();
#pragma unroll
        for (int i = 0; i < 4; ++i) {
            glds16(pa + kt + i * 8 * Dc, la + i * 8 * 64);
            glds16(pb + kt + i * 8 * Dc, lb + i * 8 * 64);
        }
        __syncthreads();
#pragma unroll
        for (int ks = 0; ks < 2; ++ks) {
            const int soff = ((ks * 4 + g) ^ swz) * 8;
            bf16x8 af[4], bf[4];
#pragma unroll
            for (int mi = 0; mi < 4; ++mi)
                af[mi] = *(const bf16x8*)&As[(wr * 64 + mi * 16 + li) * 64 + soff];
#pragma unroll
            for (int nj = 0; nj < 4; ++nj)
                bf[nj] = *(const bf16x8*)&Bs[(wc * 64 + nj * 16 + li) * 64 + soff];
#pragma unroll
            for (int mi = 0; mi < 4; ++mi)
#pragma unroll
                for (int nj = 0; nj < 4; ++nj)
                    acc[mi][nj] = __builtin_amdgcn_mfma_f32_16x16x32_bf16(
                        af[mi], bf[nj], acc[mi][nj], 0, 0, 0);
        }
    }

    const int b = row0 >> 10;

    if (z != 2) {
        // sigma-d epilogue: lane's 4 cols {li,li+16,li+32,li+48} -> sigma
        // positions 4*li..4*li+3 (contiguous): one b64 RTNE store per (mi,rr)
        const int h2 = (c0 + wc * 64) >> 6;
        const int nbase = (row0 & 1023) + wr * 64 + g * 4;
#pragma unroll
        for (int mi = 0; mi < 4; ++mi)
#pragma unroll
            for (int rr = 0; rr < 4; ++rr) {
                int n = nbase + mi * 16 + rr;
                u32x2 pk;
                pk.x = (u32)f2bf(acc[mi][0][rr] * qsc) | ((u32)f2bf(acc[mi][1][rr] * qsc) << 16);
                pk.y = (u32)f2bf(acc[mi][2][rr] * qsc) | ((u32)f2bf(acc[mi][3][rr] * qsc) << 16);
                *(u32x2*)(out + ((size_t)(b * Hc + h2) * Nc + n) * DHc + 4 * li) = pk;
            }
    } else {
        // per-wave 64x64 transpose in LDS scratch; key dim stored in
        // sigma-permuted order with the usual XOR seg swizzle.
        __syncthreads();
        u16* T = ((wave & 2) ? Bs : As) + (wave & 1) * 4096;
#pragma unroll
        for (int mi = 0; mi < 4; ++mi)
#pragma unroll
            for (int rr = 0; rr < 4; ++rr) {
                int r = mi * 16 + g * 4 + rr;
                int pp = ((r & 15) << 2) | (r >> 4);     // sigma(r)
#pragma unroll
                for (int nj = 0; nj < 4; ++nj) {
                    int c = nj * 16 + li;
                    T[c * 64 + ((((pp >> 3) ^ (c & 7)) << 3) | (pp & 7))]
                        = f2bf(acc[mi][nj][rr]);
                }
            }
        const int nseg = ls ^ lr;
#pragma unroll
        for (int i = 0; i < 8; ++i) {
            int cl = i * 8 + lr;              // local col (d)
            u16x8 val = *(const u16x8*)&T[cl * 64 + ls * 8];
            int cz = c0 + wc * 64 + cl;
            int n = (row0 & 1023) + wr * 64 + nseg * 8;
            *(u16x8*)&vo[(((size_t)(b * Hc + (cz >> 6)) * DHc + (cz & 63)) * Nc) + n] = val;
        }
    }
}

// ---------------------------------------------------------------------------
// Kernel 2: flash attention v5 — single-barrier schedule (validated r5: attn
// dropped out of top-5, < 64 us). K AND V double-buffered (32 KB); all
// tile-(it+1) glds + bias prefetch issue right after the single barrier;
// drain at the next barrier (full compute phase of cover). PQ 16 KB via
// XOR swizzle (0 bank conflicts). exp2 softmax w/ log2e-premul bias.
// Fixed-max softmax (max==0 safe); q pre-scaled by 1/32 in qkv.
// XCD swizzle: whole batch element b on XCD (id & 7); h fastest (bias reuse).
// ---------------------------------------------------------------------------
__global__ __launch_bounds__(256, 3) void attn_mfma(
    const u16* __restrict__ q, const u16* __restrict__ k,
    const u16* __restrict__ v, const u16* __restrict__ bias,
    float* __restrict__ attn_out)
{
    __shared__ u16 Ks[2][64 * 64];    // 16 KB [buf][key][kseg^(key&7)]
    __shared__ u16 VTs[2][64 * 64];   // 16 KB [buf][d][pkseg^(d&7)]
    __shared__ u16 PQ[128 * 64];      // 16 KB Q then P, XOR-swizzled rows

    const int tid = threadIdx.x;
    const int w = tid >> 6, lane = tid & 63;
    const int g = lane >> 4, li = lane & 15;
    const int lr8 = lane >> 3, ls8 = lane & 7;
    const int lseg = ls8 ^ lr8;               // swizzled staging k-seg

    // XCD-locality remap: whole batch element b on XCD (id & 7); h fastest.
    const int id = blockIdx.x;
    const int b  = id & 7;
    const int r_ = id >> 3;                   // 0..127
    const int h  = r_ & 15;
    const int qt = r_ >> 4;
    const int q0 = qt << 7;

    const u16* kbase = k + (size_t)(b * Hc + h) * Nc * DHc;
    const u16* vbase = v + (size_t)(b * Hc + h) * DHc * Nc;
    const u16* brow  = bias + ((size_t)(b * Nc) + q0 + w * 32) * Nc + 4 * li;

    // ---- prologue: issue tile-0 K+V staging first (overlap with Q setup) ----
    {
        const u16* kp = kbase + (size_t)(w * 16 + lr8) * DHc + lseg * 8;
        const u16* vp = vbase + (size_t)(w * 16 + lr8) * Nc + lseg * 8;
        glds16(kp,           &Ks[0][(w * 16) * 64]);
        glds16(kp + 8 * DHc, &Ks[0][(w * 16) * 64 + 8 * 64]);
        glds16(vp,           &VTs[0][(w * 16) * 64]);
        glds16(vp + 8 * Nc,  &VTs[0][(w * 16) * 64 + 8 * 64]);
    }

    // ---- stage Q [128][64] into PQ, swizzled (wave-private rows) ----
    {
        const int sr = tid >> 1;
        const int sh = (tid & 1) * 32;
        const int sw = (sr & 7) << 3;
        const u16* qp = q + ((size_t)((b * Hc + h) * Nc) + q0 + sr) * DHc + sh;
        u16* dst = &PQ[sr * 64];
        *(u16x8*)(dst + ((sh +  0) ^ sw)) = *(const u16x8*)(qp);
        *(u16x8*)(dst + ((sh +  8) ^ sw)) = *(const u16x8*)(qp + 8);
        *(u16x8*)(dst + ((sh + 16) ^ sw)) = *(const u16x8*)(qp + 16);
        *(u16x8*)(dst + ((sh + 24) ^ sw)) = *(const u16x8*)(qp + 24);
    }

    // bias tile 0 prefetch
    u16x4 brv[2][4];
#pragma unroll
    for (int mt = 0; mt < 2; ++mt)
#pragma unroll
        for (int r = 0; r < 4; ++r)
            brv[mt][r] = *(const u16x4*)&brow[(size_t)(mt * 16 + g * 4 + r) * Nc];

    // Q fragments (intra-wave LDS dependency only)
    bf16x8 qf[2][2];
#pragma unroll
    for (int mt = 0; mt < 2; ++mt)
#pragma unroll
        for (int ks = 0; ks < 2; ++ks)
            qf[mt][ks] = *(const bf16x8*)&PQ[(w * 32 + mt * 16 + li) * 64
                                            + ((ks * 32 + g * 8) ^ ((li & 7) << 3))];

    f32x4 o_[2][4] = {};
    float lsum[2][4] = {};

    for (int it = 0; it < 16; ++it) {
        const int cur = it & 1;
        __syncthreads();   // drains K[it]+V[it] glds (full-phase-old); syncs bufs

        u16x4 brn[2][4];
        if (it < 15) {     // issue tile it+1 staging into the other buffer
            const int k1 = (it + 1) * 64;
            const u16* kp = kbase + (size_t)(k1 + w * 16 + lr8) * DHc + lseg * 8;
            const u16* vp = vbase + (size_t)(w * 16 + lr8) * Nc + k1 + lseg * 8;
            u16* kl = &Ks[cur ^ 1][(w * 16) * 64];
            u16* vl = &VTs[cur ^ 1][(w * 16) * 64];
            glds16(kp,           kl);
            glds16(kp + 8 * DHc, kl + 8 * 64);
            glds16(vp,           vl);
            glds16(vp + 8 * Nc,  vl + 8 * 64);
#pragma unroll
            for (int mt = 0; mt < 2; ++mt)
#pragma unroll
                for (int r = 0; r < 4; ++r)
                    brn[mt][r] = *(const u16x4*)&brow[(size_t)(mt * 16 + g * 4 + r) * Nc + k1];
        }

        // --- S = Q.K^T : 16 MFMA, 8 K-frag b128 reads ---
        f32x4 sacc[2][4] = {};
        __builtin_amdgcn_s_setprio(1);
#pragma unroll
        for (int ks = 0; ks < 2; ++ks) {
            const int so = (((ks << 2) | g) ^ (li & 7)) << 3;
#pragma unroll
            for (int nt = 0; nt < 4; ++nt) {
                bf16x8 kf = *(const bf16x8*)&Ks[cur][(nt * 16 + li) * 64 + so];
                sacc[0][nt] = __builtin_amdgcn_mfma_f32_16x16x32_bf16(qf[0][ks], kf, sacc[0][nt], 0, 0, 0);
                sacc[1][nt] = __builtin_amdgcn_mfma_f32_16x16x32_bf16(qf[1][ks], kf, sacc[1][nt], 0, 0, 0);
            }
        }
        __builtin_amdgcn_s_setprio(0);

        // --- softmax: P = 2^(fma(s, log2e, bias2)); packed b64 in sigma-space
        //     (PQ rows are wave-private: no barrier between P write and read)
#pragma unroll
        for (int mt = 0; mt < 2; ++mt)
#pragma unroll
            for (int r = 0; r < 4; ++r) {
                const int qrl = w * 32 + mt * 16 + g * 4 + r;
                float pv[4];
#pragma unroll
                for (int nt = 0; nt < 4; ++nt) {
                    pv[nt] = exp2_raw(fmaf(sacc[mt][nt][r], LOG2E,
                                           bf2f(brv[mt][r][nt])));
                    lsum[mt][r] += pv[nt];
                }
                u32* dst = (u32*)&PQ[(qrl & ~7) * 64
                                     + (((qrl & 7) * 64 + li * 4) ^ ((qrl & 7) << 3))];
                dst[0] = pack2bf(pv[0], pv[1]);
                dst[1] = pack2bf(pv[2], pv[3]);
            }

        // --- O += P.V : 16 MFMA, 4 P-frag + 8 VT-frag b128 reads ---
        __builtin_amdgcn_s_setprio(1);
#pragma unroll
        for (int ks = 0; ks < 2; ++ks) {
            const int so = (((ks << 2) | g) ^ (li & 7)) << 3;
            const int po = (ks * 32 + g * 8) ^ ((li & 7) << 3);
            bf16x8 pa0 = *(const bf16x8*)&PQ[(w * 32 + li) * 64 + po];
            bf16x8 pa1 = *(const bf16x8*)&PQ[(w * 32 + 16 + li) * 64 + po];
#pragma unroll
            for (int j = 0; j < 4; ++j) {
                bf16x8 vf = *(const bf16x8*)&VTs[cur][(j * 16 + li) * 64 + so];
                o_[0][j] = __builtin_amdgcn_mfma_f32_16x16x32_bf16(pa0, vf, o_[0][j], 0, 0, 0);
                o_[1][j] = __builtin_amdgcn_mfma_f32_16x16x32_bf16(pa1, vf, o_[1][j], 0, 0, 0);
            }
        }
        __builtin_amdgcn_s_setprio(0);

        if (it < 15) {
#pragma unroll
            for (int mt = 0; mt < 2; ++mt)
#pragma unroll
                for (int r = 0; r < 4; ++r)
                    brv[mt][r] = brn[mt][r];
        }
    }

    // --- epilogue: reduce row sums across 16 li lanes, normalize, write ---
#pragma unroll
    for (int mt = 0; mt < 2; ++mt)
#pragma unroll
        for (int r = 0; r < 4; ++r) {
            float l = lsum[mt][r];
            l += __shfl_xor(l, 1);
            l += __shfl_xor(l, 2);
            l += __shfl_xor(l, 4);
            l += __shfl_xor(l, 8);
            float inv = 1.f / l;
            int qrow = q0 + w * 32 + mt * 16 + g * 4 + r;
            float* op = attn_out + ((size_t)b * Nc + qrow) * Dc + h * DHc;
#pragma unroll
            for (int j = 0; j < 4; ++j)
                op[j * 16 + li] = o_[mt][j][r] * inv;
        }
}

// ---------------------------------------------------------------------------
// Kernel 3: out = LayerNorm(relu(attn_out) + hid), in-place safe.
// One WAVE per row (was one 256-block per row with 2-level LDS reduction +
// 2 barriers). 16 floats/lane, pure shuffle reduce, no LDS, no barriers.
// 4 rows/block -> 2048 blocks. In-place safe: a row is touched by exactly
// one wave, and all its loads complete before any store.
// ---------------------------------------------------------------------------
__global__ __launch_bounds__(256) void ln_kernel(
    const float* attn_out, const float* __restrict__ hid,
    const float* __restrict__ gamma, const float* __restrict__ beta,
    float* out)
{
    const int row  = blockIdx.x * 4 + (threadIdx.x >> 6);
    const int lane = threadIdx.x & 63;
    const float* ap = attn_out + (size_t)row * Dc;
    const float* hp = hid + (size_t)row * Dc;

    float4 x[4];
    float s1 = 0.f, s2 = 0.f;
#pragma unroll
    for (int j = 0; j < 4; ++j) {
        const int c = 4 * (lane + 64 * j);
        float4 a = *(const float4*)&ap[c];
        float4 h = *(const float4*)&hp[c];
        x[j].x = fmaxf(a.x, 0.f) + h.x;
        x[j].y = fmaxf(a.y, 0.f) + h.y;
        x[j].z = fmaxf(a.z, 0.f) + h.z;
        x[j].w = fmaxf(a.w, 0.f) + h.w;
        s1 += x[j].x + x[j].y + x[j].z + x[j].w;
        s2 += x[j].x * x[j].x + x[j].y * x[j].y
            + x[j].z * x[j].z + x[j].w * x[j].w;
    }
#pragma unroll
    for (int off = 1; off < 64; off <<= 1) {
        s1 += __shfl_xor(s1, off);
        s2 += __shfl_xor(s2, off);
    }

    float mu  = s1 * (1.f / 1024.f);
    float var = s2 * (1.f / 1024.f) - mu * mu;
    float rstd = rsqrtf(var + 1e-5f);

#pragma unroll
    for (int j = 0; j < 4; ++j) {
        const int c = 4 * (lane + 64 * j);
        float4 g  = *(const float4*)&gamma[c];
        float4 be = *(const float4*)&beta[c];
        float4 r4;
        r4.x = (x[j].x - mu) * rstd * g.x + be.x;
        r4.y = (x[j].y - mu) * rstd * g.y + be.y;
        r4.z = (x[j].z - mu) * rstd * g.z + be.z;
        r4.w = (x[j].w - mu) * rstd * g.w + be.w;
        *(float4*)&out[(size_t)row * Dc + c] = r4;
    }
}

extern "C" void kernel_launch(void* const* d_in, const int* in_sizes, int n_in,
                              void* d_out, int out_size, void* d_ws, size_t ws_size,
                              hipStream_t stream) {
    const float* hid       = (const float*)d_in[0];
    const int*   adj       = (const int*)d_in[1];
    const int*   relpos    = (const int*)d_in[2];
    const float* Wq        = (const float*)d_in[3];
    const float* Wk        = (const float*)d_in[4];
    const float* Wv        = (const float*)d_in[5];
    const float* rel_table = (const float*)d_in[6];
    const float* gamma     = (const float*)d_in[7];
    const float* beta      = (const float*)d_in[8];
    float* out = (float*)d_out;

    const size_t per  = (size_t)Bc * Hc * Nc * DHc;  // 8,388,608
    const size_t wsz  = (size_t)Dc * Dc;             // 1,048,576
    u16* qb   = (u16*)d_ws;                // sigma-d, pre-scaled by 1/32
    u16* kb   = qb + per;                  // sigma-d
    u16* vb   = kb + per;                  // [B,H,DH,N] transposed+sigma-key
    u16* bias = vb + per;                  // B*N*N sigma-key-permuted, *log2e
    u16* hidb = bias + (size_t)Bc * Nc * Nc;
    u16* wqT  = hidb + (size_t)Bc * Nc * Dc;
    u16* wkT  = wqT + wsz;
    u16* wvT  = wkT + wsz;
    // total ws: ~90.2 MB

    prep_fused<<<9216, 256, 0, stream>>>(adj, relpos, rel_table, bias,
                                         hid, hidb, Wq, Wk, Wv, wqT, wkT, wvT);
    qkv_mfma<<<dim3(64, 24), 256, 0, stream>>>(hidb, wqT, wkT, wvT, qb, kb, vb);
    attn_mfma<<<1024, 256, 0, stream>>>(qb, kb, vb, bias, out);
    ln_kernel<<<2048, 256, 0, stream>>>(out, hid, gamma, beta, out);
}